// Round 14
// baseline (341.604 us; speedup 1.0000x reference)
//
#include <hip/hip_runtime.h>
#include <hip/hip_fp16.h>

#define NN 100000
#define EE 1600000
#define SCAN_CHUNK 1024
#define NBLK ((NN + SCAN_CHUNK - 1) / SCAN_CHUNK)  // 98
#define NGRP 8                       // dst groups (one per XCD cohort)
#define GR ((NN + NGRP - 1) / NGRP)  // 12500 dst nodes per group
#define NSLICE 128                   // edge slices (full occupancy: 1024 blocks)
#define ES (EE / NSLICE)             // 12500 edges per slice

typedef _Float16 f16x8 __attribute__((ext_vector_type(8)));
typedef float f32x4 __attribute__((ext_vector_type(4)));

// ---------- W pre-transpose + fp16 convert: Wt[n][k] = (half)W[k][n] ----------
__global__ __launch_bounds__(256) void wtrans_k(const float* __restrict__ W,
                                                __half* __restrict__ Wt) {
    int t = blockIdx.x * 256 + threadIdx.x;  // 0..16383
    int k = t >> 7, n = t & 127;
    Wt[n * 128 + k] = __float2half(W[k * 128 + n]);
}

// ---------- MFMA GEMM (Nx128)@(128x128), fp16 in/out, fused el/er ----------
template <int INHALF>
__global__ __launch_bounds__(256) void gemm_el_k(const void* __restrict__ Xv,
                                                 const __half* __restrict__ Wt,
                                                 const float* __restrict__ al,
                                                 const float* __restrict__ ar,
                                                 __half* __restrict__ Hout,
                                                 float* __restrict__ el,
                                                 float* __restrict__ er) {
    __shared__ alignas(16) unsigned short Xs[64 * 128];
    __shared__ alignas(16) unsigned short Ws[128 * 128];
    int t = threadIdx.x;
    int row0 = blockIdx.x * 64;

    // stage Wt -> Ws (2048 x 16B chunks)
    {
        const uint4* g = (const uint4*)Wt;
#pragma unroll
        for (int j = 0; j < 8; ++j) {
            int c = j * 256 + t;
            uint4 v = g[c];
            int n = c >> 4, kb = (c & 15) << 4;
            *(uint4*)((char*)Ws + n * 256 + (kb ^ ((n & 7) << 4))) = v;
        }
    }
    // stage X -> Xs (1024 x 16B fp16 chunks), fp32->fp16 convert if !INHALF
#pragma unroll
    for (int j = 0; j < 4; ++j) {
        int c = j * 256 + t;
        int row = c >> 4, kb = (c & 15) << 4;
        int grow = row0 + row; if (grow >= NN) grow = NN - 1;
        uint4 pk;
        if (INHALF) {
            pk = ((const uint4*)Xv)[(size_t)grow * 16 + (c & 15)];
        } else {
            const float4* xp = (const float4*)Xv + (size_t)grow * 32 + (c & 15) * 2;
            float4 v0 = xp[0], v1 = xp[1];
            __half2 h01 = __floats2half2_rn(v0.x, v0.y);
            __half2 h23 = __floats2half2_rn(v0.z, v0.w);
            __half2 h45 = __floats2half2_rn(v1.x, v1.y);
            __half2 h67 = __floats2half2_rn(v1.z, v1.w);
            pk = make_uint4(__builtin_bit_cast(unsigned, h01),
                            __builtin_bit_cast(unsigned, h23),
                            __builtin_bit_cast(unsigned, h45),
                            __builtin_bit_cast(unsigned, h67));
        }
        *(uint4*)((char*)Xs + row * 256 + (kb ^ ((row & 7) << 4))) = pk;
    }
    __syncthreads();

    int w = t >> 6, lane = t & 63;
    int lr = lane & 15, lg = lane >> 4;
    int arow = w * 16 + lr;

    f32x4 acc[8] = {};
#pragma unroll
    for (int ks = 0; ks < 4; ++ks) {
        int kb = ks * 64 + lg * 16;
        f16x8 a = *(const f16x8*)((char*)Xs + arow * 256 + (kb ^ ((arow & 7) << 4)));
#pragma unroll
        for (int ct = 0; ct < 8; ++ct) {
            int brow = ct * 16 + lr;
            f16x8 b = *(const f16x8*)((char*)Ws + brow * 256 + (kb ^ ((brow & 7) << 4)));
            acc[ct] = __builtin_amdgcn_mfma_f32_16x16x32_f16(a, b, acc[ct], 0, 0, 0);
        }
    }

    // ---- store h (fp16) : lane holds C[lg*4+r][ct*16+lr] ----
#pragma unroll
    for (int r = 0; r < 4; ++r) {
        int grow = row0 + w * 16 + lg * 4 + r;
        if (grow < NN) {
            __half* hp = Hout + (size_t)grow * 128 + lr;
#pragma unroll
            for (int ct = 0; ct < 8; ++ct)
                hp[ct * 16] = __float2half(acc[ct][r]);
        }
    }
    // ---- fused el/er from fp32 accumulators ----
    float alv[8], arv[8];
#pragma unroll
    for (int ct = 0; ct < 8; ++ct) {
        alv[ct] = al[ct * 16 + lr];
        arv[ct] = ar[ct * 16 + lr];
    }
#pragma unroll
    for (int r = 0; r < 4; ++r) {
        int grow = row0 + w * 16 + lg * 4 + r;
#pragma unroll
        for (int hd = 0; hd < 4; ++hd) {
            float pl = acc[2 * hd][r] * alv[2 * hd] + acc[2 * hd + 1][r] * alv[2 * hd + 1];
            float pr = acc[2 * hd][r] * arv[2 * hd] + acc[2 * hd + 1][r] * arv[2 * hd + 1];
#pragma unroll
            for (int off = 1; off < 16; off <<= 1) {
                pl += __shfl_xor(pl, off, 64);
                pr += __shfl_xor(pr, off, 64);
            }
            if (lr == 0 && grow < NN) {
                el[grow * 4 + hd] = pl;
                er[grow * 4 + hd] = pr;
            }
        }
    }
}

// ---------------- CSR build (once per call) ----------------
__global__ void degcount_k(const int* __restrict__ dst, int* __restrict__ deg) {
    int e = blockIdx.x * blockDim.x + threadIdx.x;
    if (e < EE) atomicAdd(&deg[dst[e]], 1);
}

__global__ __launch_bounds__(256) void blocksum_k(const int* __restrict__ deg,
                                                  int* __restrict__ bsum) {
    int b = blockIdx.x, t = threadIdx.x;
    int base = b * SCAN_CHUNK + t * 4;
    int s = 0;
    if (base + 3 < NN) {
        int4 v = *(const int4*)&deg[base];
        s = v.x + v.y + v.z + v.w;
    } else {
        for (int i = base; i < NN; ++i) s += deg[i];
    }
#pragma unroll
    for (int off = 1; off < 64; off <<= 1) s += __shfl_xor(s, off, 64);
    __shared__ int wsum[4];
    if ((t & 63) == 0) wsum[t >> 6] = s;
    __syncthreads();
    if (t == 0) bsum[b] = wsum[0] + wsum[1] + wsum[2] + wsum[3];
}

__global__ __launch_bounds__(128) void bscan_k(const int* __restrict__ bsum,
                                               int* __restrict__ boff,
                                               int* __restrict__ rowptr) {
    __shared__ int sh[128];
    int t = threadIdx.x;
    int v = (t < NBLK) ? bsum[t] : 0;
    sh[t] = v;
    __syncthreads();
    for (int off = 1; off < 128; off <<= 1) {
        int u = (t >= off) ? sh[t - off] : 0;
        __syncthreads();
        sh[t] += u;
        __syncthreads();
    }
    if (t < NBLK) boff[t] = sh[t] - v;
    if (t == 0) rowptr[NN] = EE;
}

__global__ __launch_bounds__(256) void scanout_k(const int* __restrict__ deg,
                                                 const int* __restrict__ boff,
                                                 int* __restrict__ rowptr,
                                                 int* __restrict__ cursor) {
    int b = blockIdx.x, t = threadIdx.x;
    int base = b * SCAN_CHUNK + t * 4;
    int v0 = 0, v1 = 0, v2 = 0, v3 = 0;
    if (base + 3 < NN) {
        int4 v = *(const int4*)&deg[base];
        v0 = v.x; v1 = v.y; v2 = v.z; v3 = v.w;
    } else if (base < NN) {
        v0 = deg[base];
        if (base + 1 < NN) v1 = deg[base + 1];
        if (base + 2 < NN) v2 = deg[base + 2];
    }
    int tot = v0 + v1 + v2 + v3;
    __shared__ int sh[256];
    sh[t] = tot;
    __syncthreads();
    for (int off = 1; off < 256; off <<= 1) {
        int u = (t >= off) ? sh[t - off] : 0;
        __syncthreads();
        sh[t] += u;
        __syncthreads();
    }
    int ex = sh[t] - tot + boff[b];
    if (base + 3 < NN) {
        int4 rv = make_int4(ex, ex + v0, ex + v0 + v1, ex + v0 + v1 + v2);
        *(int4*)&rowptr[base] = rv;
        *(int4*)&cursor[base] = rv;
    } else if (base < NN) {
        rowptr[base] = ex; cursor[base] = ex;
        if (base + 1 < NN) { rowptr[base + 1] = ex + v0; cursor[base + 1] = ex + v0; }
        if (base + 2 < NN) { rowptr[base + 2] = ex + v0 + v1; cursor[base + 2] = ex + v0 + v1; }
    }
}

// XCD-cohort scatter: block bid -> dst group g = bid&7 (same-XCD cohort under
// round-robin dispatch), edge slice bid>>3 (128 slices -> 1024 blocks = full
// occupancy at 8 waves/block).
__global__ __launch_bounds__(512) void scatter_xcd_k(const int* __restrict__ src,
                                                     const int* __restrict__ dst,
                                                     int* __restrict__ cursor,
                                                     int* __restrict__ csr_src) {
    int g = blockIdx.x & (NGRP - 1);
    int slice = blockIdx.x >> 3;
    int lo = g * GR;
    int e_beg = slice * ES, e_end = e_beg + ES;
    for (int e0 = e_beg + threadIdx.x * 4; e0 < e_end; e0 += 512 * 4) {
        int4 d4 = *(const int4*)&dst[e0];
        int4 s4 = *(const int4*)&src[e0];
        int dd[4] = {d4.x, d4.y, d4.z, d4.w};
        int ss[4] = {s4.x, s4.y, s4.z, s4.w};
#pragma unroll
        for (int j = 0; j < 4; ++j) {
            unsigned r = (unsigned)(dd[j] - lo);
            if (r < (unsigned)GR) {
                int p = atomicAdd(&cursor[dd[j]], 1);
                csr_src[p] = ss[j];
            }
        }
    }
}

// ---------- fused per-node softmax + aggregation ----------
// ONE WAVE PER WORKGROUP (64 thr). lane = hd*16 + sub. Uniform branch:
// deg<=16 half-chunk. Alpha broadcast within 16-group via static ds_swizzle
// pattern (lane&16)|i — literal constants only (frontend requirement).
#define BC16(x, I) __uint_as_float(__builtin_amdgcn_ds_swizzle( \
    __float_as_uint(x), ((I) << 5) | 0x10))

#define AGG_STEP(av, hvp, I)                      \
    {                                             \
        float ai = BC16(av, I);                   \
        float2 f = __half22float2((hvp)[I]);      \
        acc0 = fmaf(ai, f.x, acc0);               \
        acc1 = fmaf(ai, f.y, acc1);               \
    }

#define AGG16(av, hvp)                                                       \
    AGG_STEP(av, hvp, 0)  AGG_STEP(av, hvp, 1)  AGG_STEP(av, hvp, 2)         \
    AGG_STEP(av, hvp, 3)  AGG_STEP(av, hvp, 4)  AGG_STEP(av, hvp, 5)         \
    AGG_STEP(av, hvp, 6)  AGG_STEP(av, hvp, 7)  AGG_STEP(av, hvp, 8)         \
    AGG_STEP(av, hvp, 9)  AGG_STEP(av, hvp, 10) AGG_STEP(av, hvp, 11)        \
    AGG_STEP(av, hvp, 12) AGG_STEP(av, hvp, 13) AGG_STEP(av, hvp, 14)        \
    AGG_STEP(av, hvp, 15)

template <int FINAL>
__global__ __launch_bounds__(64) void gat_agg_k(const int* __restrict__ rowptr,
                                                const int* __restrict__ csr_src,
                                                const float* __restrict__ el,
                                                const float* __restrict__ er,
                                                const __half* __restrict__ h,
                                                const float* __restrict__ bias,
                                                void* __restrict__ outv,
                                                const float* __restrict__ Wf,
                                                const float* __restrict__ bf) {
    int wave = blockIdx.x;
    int lane = threadIdx.x;
    int row = rowptr[wave], end = rowptr[wave + 1];
    int hd = lane >> 4, sub = lane & 15;
    float erd = er[wave * 4 + hd];
    const __half2* hbase = (const __half2*)h + lane;  // + si*64 per gather

    float dpart = 0.f, acc0 = 0.f, acc1 = 0.f;
    for (int base = row; base < end; base += 32) {
        int c = end - base;
        int s0 = csr_src[base + (sub < c ? sub : 0)];
        float a0 = 0.f;
        {
            float v = el[s0 * 4 + hd] + erd;
            v = (v >= 0.f) ? v : 0.2f * v;
            if (sub < c) a0 = __expf(v);
        }
        if (c > 16) {
            int i1 = 16 + sub;
            int s1 = csr_src[base + (i1 < c ? i1 : 0)];
            float a1 = 0.f;
            {
                float v = el[s1 * 4 + hd] + erd;
                v = (v >= 0.f) ? v : 0.2f * v;
                if (i1 < c) a1 = __expf(v);
            }
            dpart += a0 + a1;
            __half2 hv[32];
#pragma unroll
            for (int i = 0; i < 16; ++i) {
                int si = __builtin_amdgcn_readlane(s0, i);
                hv[i] = hbase[si * 64];
            }
#pragma unroll
            for (int i = 0; i < 16; ++i) {
                int si = __builtin_amdgcn_readlane(s1, i);
                hv[16 + i] = hbase[si * 64];
            }
            AGG16(a0, hv)
            AGG16(a1, (hv + 16))
        } else {
            dpart += a0;
            __half2 hv[16];
#pragma unroll
            for (int i = 0; i < 16; ++i) {
                int si = __builtin_amdgcn_readlane(s0, i);
                hv[i] = hbase[si * 64];
            }
            AGG16(a0, hv)
        }
    }
    float denom = dpart;
#pragma unroll
    for (int off = 1; off < 16; off <<= 1) denom += __shfl_xor(denom, off, 64);
    float inv = 1.f / fmaxf(denom, 1e-9f);
    float2 bv = *(const float2*)&bias[lane * 2];
    float o0 = acc0 * inv + bv.x;
    float o1 = acc1 * inv + bv.y;

    if (FINAL) {
        float* out = (float*)outv;
        float4 wf = *(const float4*)&Wf[lane * 4];
        float c0 = o0 * wf.x + o1 * wf.z;
        float c1 = o0 * wf.y + o1 * wf.w;
#pragma unroll
        for (int off = 1; off < 64; off <<= 1) {
            c0 += __shfl_xor(c0, off, 64);
            c1 += __shfl_xor(c1, off, 64);
        }
        if (lane == 0) {
            float2 res = make_float2(c0 + bf[0], c1 + bf[1]);
            *(float2*)&out[(size_t)wave * 2] = res;
        }
    } else {
        __half* out = (__half*)outv;
        *(__half2*)&out[(size_t)wave * 128 + lane * 2] = __floats2half2_rn(o0, o1);
    }
}

extern "C" void kernel_launch(void* const* d_in, const int* in_sizes, int n_in,
                              void* d_out, int out_size, void* d_ws, size_t ws_size,
                              hipStream_t stream) {
    const float* x   = (const float*)d_in[0];
    const int*   src = (const int*)d_in[1];
    const int*   dst = (const int*)d_in[2];
    const float* W1  = (const float*)d_in[3];
    const float* al1 = (const float*)d_in[4];
    const float* ar1 = (const float*)d_in[5];
    const float* b1  = (const float*)d_in[6];
    const float* W2  = (const float*)d_in[7];
    const float* al2 = (const float*)d_in[8];
    const float* ar2 = (const float*)d_in[9];
    const float* b2  = (const float*)d_in[10];
    const float* Wf  = (const float*)d_in[11];
    const float* bf  = (const float*)d_in[12];
    float* out = (float*)d_out;

    __half* bufH  = (__half*)d_ws;                       // N*128 fp16 (h)
    __half* bufO  = bufH + (size_t)NN * 128;             // N*128 fp16 (layer1 out)
    float* el     = (float*)(bufO + (size_t)NN * 128);   // N*4
    float* er     = el + NN * 4;                         // N*4
    int* deg      = (int*)(er + NN * 4);                 // N
    int* rowptr   = deg + NN;                            // N+1
    int* cursor   = rowptr + NN + 1;                     // N
    int* csr_src  = cursor + NN;                         // E
    int* bsum     = csr_src + EE;                        // NBLK
    int* boff     = bsum + NBLK;                         // NBLK
    __half* Wt1   = (__half*)(boff + NBLK);              // 128*128 fp16
    __half* Wt2   = Wt1 + 128 * 128;                     // 128*128 fp16

    const int T = 256;
    int gE    = (EE + T - 1) / T;
    int gGemm = (NN + 63) / 64;    // 64 rows per block

    // W pre-transpose/convert + CSR build (independent of GEMM inputs)
    wtrans_k<<<64, T, 0, stream>>>(W1, Wt1);
    wtrans_k<<<64, T, 0, stream>>>(W2, Wt2);
    (void)hipMemsetAsync(deg, 0, NN * sizeof(int), stream);
    degcount_k<<<gE, T, 0, stream>>>(dst, deg);
    blocksum_k<<<NBLK, T, 0, stream>>>(deg, bsum);
    bscan_k<<<1, 128, 0, stream>>>(bsum, boff, rowptr);
    scanout_k<<<NBLK, T, 0, stream>>>(deg, boff, rowptr, cursor);
    scatter_xcd_k<<<NGRP * NSLICE, 512, 0, stream>>>(src, dst, cursor, csr_src);

    // layer 1
    gemm_el_k<0><<<gGemm, T, 0, stream>>>(x, Wt1, al1, ar1, bufH, el, er);
    gat_agg_k<0><<<NN, 64, 0, stream>>>(rowptr, csr_src, el, er, bufH, b1, bufO,
                                        nullptr, nullptr);
    // layer 2 (classifier fused into aggregation epilogue)
    gemm_el_k<1><<<gGemm, T, 0, stream>>>(bufO, Wt2, al2, ar2, bufH, el, er);
    gat_agg_k<1><<<NN, 64, 0, stream>>>(rowptr, csr_src, el, er, bufH, b2, out,
                                        Wf, bf);
}

// Round 15
// 309.154 us; speedup vs baseline: 1.1050x; 1.1050x over previous
//
#include <hip/hip_runtime.h>
#include <hip/hip_fp16.h>

#define NN 100000
#define EE 1600000
#define SCAN_CHUNK 1024
#define NBLK ((NN + SCAN_CHUNK - 1) / SCAN_CHUNK)  // 98
#define NPB 256                      // partition blocks
#define EPB (EE / NPB)               // 6250 edges per partition block
#define NGRP2 200                    // dst ranges (counting-sort blocks)
#define GR2 (NN / NGRP2)             // 500 nodes per range
#define CCAP 10240                   // LDS sort capacity (mean 8000, +25 sigma)

typedef _Float16 f16x8 __attribute__((ext_vector_type(8)));
typedef float f32x4 __attribute__((ext_vector_type(4)));

// ---------- W pre-transpose + fp16 convert: Wt[n][k] = (half)W[k][n] ----------
__global__ __launch_bounds__(256) void wtrans_k(const float* __restrict__ W,
                                                __half* __restrict__ Wt) {
    int t = blockIdx.x * 256 + threadIdx.x;  // 0..16383
    int k = t >> 7, n = t & 127;
    Wt[n * 128 + k] = __float2half(W[k * 128 + n]);
}

// ---------- MFMA GEMM (Nx128)@(128x128), fp16 in/out, fused el/er ----------
template <int INHALF>
__global__ __launch_bounds__(256) void gemm_el_k(const void* __restrict__ Xv,
                                                 const __half* __restrict__ Wt,
                                                 const float* __restrict__ al,
                                                 const float* __restrict__ ar,
                                                 __half* __restrict__ Hout,
                                                 float* __restrict__ el,
                                                 float* __restrict__ er) {
    __shared__ alignas(16) unsigned short Xs[64 * 128];
    __shared__ alignas(16) unsigned short Ws[128 * 128];
    int t = threadIdx.x;
    int row0 = blockIdx.x * 64;

    // stage Wt -> Ws (2048 x 16B chunks)
    {
        const uint4* g = (const uint4*)Wt;
#pragma unroll
        for (int j = 0; j < 8; ++j) {
            int c = j * 256 + t;
            uint4 v = g[c];
            int n = c >> 4, kb = (c & 15) << 4;
            *(uint4*)((char*)Ws + n * 256 + (kb ^ ((n & 7) << 4))) = v;
        }
    }
    // stage X -> Xs (1024 x 16B fp16 chunks), fp32->fp16 convert if !INHALF
#pragma unroll
    for (int j = 0; j < 4; ++j) {
        int c = j * 256 + t;
        int row = c >> 4, kb = (c & 15) << 4;
        int grow = row0 + row; if (grow >= NN) grow = NN - 1;
        uint4 pk;
        if (INHALF) {
            pk = ((const uint4*)Xv)[(size_t)grow * 16 + (c & 15)];
        } else {
            const float4* xp = (const float4*)Xv + (size_t)grow * 32 + (c & 15) * 2;
            float4 v0 = xp[0], v1 = xp[1];
            __half2 h01 = __floats2half2_rn(v0.x, v0.y);
            __half2 h23 = __floats2half2_rn(v0.z, v0.w);
            __half2 h45 = __floats2half2_rn(v1.x, v1.y);
            __half2 h67 = __floats2half2_rn(v1.z, v1.w);
            pk = make_uint4(__builtin_bit_cast(unsigned, h01),
                            __builtin_bit_cast(unsigned, h23),
                            __builtin_bit_cast(unsigned, h45),
                            __builtin_bit_cast(unsigned, h67));
        }
        *(uint4*)((char*)Xs + row * 256 + (kb ^ ((row & 7) << 4))) = pk;
    }
    __syncthreads();

    int w = t >> 6, lane = t & 63;
    int lr = lane & 15, lg = lane >> 4;
    int arow = w * 16 + lr;

    f32x4 acc[8] = {};
#pragma unroll
    for (int ks = 0; ks < 4; ++ks) {
        int kb = ks * 64 + lg * 16;
        f16x8 a = *(const f16x8*)((char*)Xs + arow * 256 + (kb ^ ((arow & 7) << 4)));
#pragma unroll
        for (int ct = 0; ct < 8; ++ct) {
            int brow = ct * 16 + lr;
            f16x8 b = *(const f16x8*)((char*)Ws + brow * 256 + (kb ^ ((brow & 7) << 4)));
            acc[ct] = __builtin_amdgcn_mfma_f32_16x16x32_f16(a, b, acc[ct], 0, 0, 0);
        }
    }

    // ---- store h (fp16) : lane holds C[lg*4+r][ct*16+lr] ----
#pragma unroll
    for (int r = 0; r < 4; ++r) {
        int grow = row0 + w * 16 + lg * 4 + r;
        if (grow < NN) {
            __half* hp = Hout + (size_t)grow * 128 + lr;
#pragma unroll
            for (int ct = 0; ct < 8; ++ct)
                hp[ct * 16] = __float2half(acc[ct][r]);
        }
    }
    // ---- fused el/er from fp32 accumulators ----
    float alv[8], arv[8];
#pragma unroll
    for (int ct = 0; ct < 8; ++ct) {
        alv[ct] = al[ct * 16 + lr];
        arv[ct] = ar[ct * 16 + lr];
    }
#pragma unroll
    for (int r = 0; r < 4; ++r) {
        int grow = row0 + w * 16 + lg * 4 + r;
#pragma unroll
        for (int hd = 0; hd < 4; ++hd) {
            float pl = acc[2 * hd][r] * alv[2 * hd] + acc[2 * hd + 1][r] * alv[2 * hd + 1];
            float pr = acc[2 * hd][r] * arv[2 * hd] + acc[2 * hd + 1][r] * arv[2 * hd + 1];
#pragma unroll
            for (int off = 1; off < 16; off <<= 1) {
                pl += __shfl_xor(pl, off, 64);
                pr += __shfl_xor(pr, off, 64);
            }
            if (lr == 0 && grow < NN) {
                el[grow * 4 + hd] = pl;
                er[grow * 4 + hd] = pr;
            }
        }
    }
}

// ---------------- CSR build: partition + LDS counting sort ----------------
// Pass A: per-block x per-range histogram + fused global degree count.
__global__ __launch_bounds__(512) void partA_k(const int* __restrict__ dst,
                                               int* __restrict__ deg,
                                               int* __restrict__ gcnt) {
    __shared__ int cnt[NGRP2];
    int b = blockIdx.x, t = threadIdx.x;
    for (int i = t; i < NGRP2; i += 512) cnt[i] = 0;
    __syncthreads();
    int e_beg = b * EPB;
    for (int e = e_beg + t; e < e_beg + EPB; e += 512) {
        int d = dst[e];
        atomicAdd(&deg[d], 1);
        atomicAdd(&cnt[d / GR2], 1);
    }
    __syncthreads();
    for (int i = t; i < NGRP2; i += 512) gcnt[i * NPB + b] = cnt[i];
}

// Exclusive scan of NGRP2*NPB = 51200 counters (g-major).
__global__ __launch_bounds__(1024) void pscan_k(const int* __restrict__ gcnt,
                                                int* __restrict__ poff) {
    __shared__ int sh[1024];
    int t = threadIdx.x;
    const int CH = (NGRP2 * NPB) / 1024;  // 50
    int base = t * CH;
    int s = 0;
    for (int i = 0; i < CH; ++i) s += gcnt[base + i];
    sh[t] = s;
    __syncthreads();
    for (int off = 1; off < 1024; off <<= 1) {
        int u = (t >= off) ? sh[t - off] : 0;
        __syncthreads();
        sh[t] += u;
        __syncthreads();
    }
    int ex = sh[t] - s;
    for (int i = 0; i < CH; ++i) {
        int v = gcnt[base + i];
        poff[base + i] = ex;
        ex += v;
    }
}

// Pass B: partition edges into per-range contiguous (src,dst) buffers.
__global__ __launch_bounds__(512) void partB_k(const int* __restrict__ src,
                                               const int* __restrict__ dst,
                                               const int* __restrict__ poff,
                                               int2* __restrict__ ebuf) {
    __shared__ int cur[NGRP2];
    int b = blockIdx.x, t = threadIdx.x;
    for (int i = t; i < NGRP2; i += 512) cur[i] = poff[i * NPB + b];
    __syncthreads();
    int e_beg = b * EPB;
    for (int e = e_beg + t; e < e_beg + EPB; e += 512) {
        int d = dst[e], s = src[e];
        int p = atomicAdd(&cur[d / GR2], 1);
        ebuf[p] = make_int2(s, d);
    }
}

// Pass C: per-range LDS counting sort -> sequential csr_src dump.
__global__ __launch_bounds__(512) void partC_k(const int2* __restrict__ ebuf,
                                               const int* __restrict__ poff,
                                               const int* __restrict__ rowptr,
                                               int* __restrict__ csr_src) {
    __shared__ int lsrc[CCAP];
    __shared__ int lcur[GR2];
    int g = blockIdx.x, t = threadIdx.x;
    int nbase = g * GR2;
    int csrbase = rowptr[nbase];
    for (int i = t; i < GR2; i += 512) lcur[i] = rowptr[nbase + i] - csrbase;
    __syncthreads();
    int beg = poff[g * NPB];
    int end = (g == NGRP2 - 1) ? EE : poff[(g + 1) * NPB];
    for (int e = beg + t; e < end; e += 512) {
        int2 sd = ebuf[e];
        int p = atomicAdd(&lcur[sd.y - nbase], 1);
        if (p < CCAP) lsrc[p] = sd.x;
    }
    __syncthreads();
    int len = end - beg; if (len > CCAP) len = CCAP;
    for (int i = t; i < len; i += 512) csr_src[csrbase + i] = lsrc[i];
}

// ---------------- rowptr build (unchanged scan over deg) ----------------
__global__ __launch_bounds__(256) void blocksum_k(const int* __restrict__ deg,
                                                  int* __restrict__ bsum) {
    int b = blockIdx.x, t = threadIdx.x;
    int base = b * SCAN_CHUNK + t * 4;
    int s = 0;
    if (base + 3 < NN) {
        int4 v = *(const int4*)&deg[base];
        s = v.x + v.y + v.z + v.w;
    } else {
        for (int i = base; i < NN; ++i) s += deg[i];
    }
#pragma unroll
    for (int off = 1; off < 64; off <<= 1) s += __shfl_xor(s, off, 64);
    __shared__ int wsum[4];
    if ((t & 63) == 0) wsum[t >> 6] = s;
    __syncthreads();
    if (t == 0) bsum[b] = wsum[0] + wsum[1] + wsum[2] + wsum[3];
}

__global__ __launch_bounds__(128) void bscan_k(const int* __restrict__ bsum,
                                               int* __restrict__ boff,
                                               int* __restrict__ rowptr) {
    __shared__ int sh[128];
    int t = threadIdx.x;
    int v = (t < NBLK) ? bsum[t] : 0;
    sh[t] = v;
    __syncthreads();
    for (int off = 1; off < 128; off <<= 1) {
        int u = (t >= off) ? sh[t - off] : 0;
        __syncthreads();
        sh[t] += u;
        __syncthreads();
    }
    if (t < NBLK) boff[t] = sh[t] - v;
    if (t == 0) rowptr[NN] = EE;
}

__global__ __launch_bounds__(256) void scanout_k(const int* __restrict__ deg,
                                                 const int* __restrict__ boff,
                                                 int* __restrict__ rowptr) {
    int b = blockIdx.x, t = threadIdx.x;
    int base = b * SCAN_CHUNK + t * 4;
    int v0 = 0, v1 = 0, v2 = 0, v3 = 0;
    if (base + 3 < NN) {
        int4 v = *(const int4*)&deg[base];
        v0 = v.x; v1 = v.y; v2 = v.z; v3 = v.w;
    } else if (base < NN) {
        v0 = deg[base];
        if (base + 1 < NN) v1 = deg[base + 1];
        if (base + 2 < NN) v2 = deg[base + 2];
    }
    int tot = v0 + v1 + v2 + v3;
    __shared__ int sh[256];
    sh[t] = tot;
    __syncthreads();
    for (int off = 1; off < 256; off <<= 1) {
        int u = (t >= off) ? sh[t - off] : 0;
        __syncthreads();
        sh[t] += u;
        __syncthreads();
    }
    int ex = sh[t] - tot + boff[b];
    if (base + 3 < NN) {
        int4 rv = make_int4(ex, ex + v0, ex + v0 + v1, ex + v0 + v1 + v2);
        *(int4*)&rowptr[base] = rv;
    } else if (base < NN) {
        rowptr[base] = ex;
        if (base + 1 < NN) rowptr[base + 1] = ex + v0;
        if (base + 2 < NN) rowptr[base + 2] = ex + v0 + v1;
    }
}

// ---------- fused per-node softmax + aggregation ----------
#define BC16(x, I) __uint_as_float(__builtin_amdgcn_ds_swizzle( \
    __float_as_uint(x), ((I) << 5) | 0x10))

#define AGG_STEP(av, hvp, I)                      \
    {                                             \
        float ai = BC16(av, I);                   \
        float2 f = __half22float2((hvp)[I]);      \
        acc0 = fmaf(ai, f.x, acc0);               \
        acc1 = fmaf(ai, f.y, acc1);               \
    }

#define AGG16(av, hvp)                                                       \
    AGG_STEP(av, hvp, 0)  AGG_STEP(av, hvp, 1)  AGG_STEP(av, hvp, 2)         \
    AGG_STEP(av, hvp, 3)  AGG_STEP(av, hvp, 4)  AGG_STEP(av, hvp, 5)         \
    AGG_STEP(av, hvp, 6)  AGG_STEP(av, hvp, 7)  AGG_STEP(av, hvp, 8)         \
    AGG_STEP(av, hvp, 9)  AGG_STEP(av, hvp, 10) AGG_STEP(av, hvp, 11)        \
    AGG_STEP(av, hvp, 12) AGG_STEP(av, hvp, 13) AGG_STEP(av, hvp, 14)        \
    AGG_STEP(av, hvp, 15)

template <int FINAL>
__global__ __launch_bounds__(64) void gat_agg_k(const int* __restrict__ rowptr,
                                                const int* __restrict__ csr_src,
                                                const float* __restrict__ el,
                                                const float* __restrict__ er,
                                                const __half* __restrict__ h,
                                                const float* __restrict__ bias,
                                                void* __restrict__ outv,
                                                const float* __restrict__ Wf,
                                                const float* __restrict__ bf) {
    int wave = blockIdx.x;
    int lane = threadIdx.x;
    int row = rowptr[wave], end = rowptr[wave + 1];
    int hd = lane >> 4, sub = lane & 15;
    float erd = er[wave * 4 + hd];
    const __half2* hbase = (const __half2*)h + lane;  // + si*64 per gather

    float dpart = 0.f, acc0 = 0.f, acc1 = 0.f;
    for (int base = row; base < end; base += 32) {
        int c = end - base;
        int s0 = csr_src[base + (sub < c ? sub : 0)];
        float a0 = 0.f;
        {
            float v = el[s0 * 4 + hd] + erd;
            v = (v >= 0.f) ? v : 0.2f * v;
            if (sub < c) a0 = __expf(v);
        }
        if (c > 16) {
            int i1 = 16 + sub;
            int s1 = csr_src[base + (i1 < c ? i1 : 0)];
            float a1 = 0.f;
            {
                float v = el[s1 * 4 + hd] + erd;
                v = (v >= 0.f) ? v : 0.2f * v;
                if (i1 < c) a1 = __expf(v);
            }
            dpart += a0 + a1;
            __half2 hv[32];
#pragma unroll
            for (int i = 0; i < 16; ++i) {
                int si = __builtin_amdgcn_readlane(s0, i);
                hv[i] = hbase[si * 64];
            }
#pragma unroll
            for (int i = 0; i < 16; ++i) {
                int si = __builtin_amdgcn_readlane(s1, i);
                hv[16 + i] = hbase[si * 64];
            }
            AGG16(a0, hv)
            AGG16(a1, (hv + 16))
        } else {
            dpart += a0;
            __half2 hv[16];
#pragma unroll
            for (int i = 0; i < 16; ++i) {
                int si = __builtin_amdgcn_readlane(s0, i);
                hv[i] = hbase[si * 64];
            }
            AGG16(a0, hv)
        }
    }
    float denom = dpart;
#pragma unroll
    for (int off = 1; off < 16; off <<= 1) denom += __shfl_xor(denom, off, 64);
    float inv = 1.f / fmaxf(denom, 1e-9f);
    float2 bv = *(const float2*)&bias[lane * 2];
    float o0 = acc0 * inv + bv.x;
    float o1 = acc1 * inv + bv.y;

    if (FINAL) {
        float* out = (float*)outv;
        float4 wf = *(const float4*)&Wf[lane * 4];
        float c0 = o0 * wf.x + o1 * wf.z;
        float c1 = o0 * wf.y + o1 * wf.w;
#pragma unroll
        for (int off = 1; off < 64; off <<= 1) {
            c0 += __shfl_xor(c0, off, 64);
            c1 += __shfl_xor(c1, off, 64);
        }
        if (lane == 0) {
            float2 res = make_float2(c0 + bf[0], c1 + bf[1]);
            *(float2*)&out[(size_t)wave * 2] = res;
        }
    } else {
        __half* out = (__half*)outv;
        *(__half2*)&out[(size_t)wave * 128 + lane * 2] = __floats2half2_rn(o0, o1);
    }
}

extern "C" void kernel_launch(void* const* d_in, const int* in_sizes, int n_in,
                              void* d_out, int out_size, void* d_ws, size_t ws_size,
                              hipStream_t stream) {
    const float* x   = (const float*)d_in[0];
    const int*   src = (const int*)d_in[1];
    const int*   dst = (const int*)d_in[2];
    const float* W1  = (const float*)d_in[3];
    const float* al1 = (const float*)d_in[4];
    const float* ar1 = (const float*)d_in[5];
    const float* b1  = (const float*)d_in[6];
    const float* W2  = (const float*)d_in[7];
    const float* al2 = (const float*)d_in[8];
    const float* ar2 = (const float*)d_in[9];
    const float* b2  = (const float*)d_in[10];
    const float* Wf  = (const float*)d_in[11];
    const float* bf  = (const float*)d_in[12];
    float* out = (float*)d_out;

    __half* bufH  = (__half*)d_ws;                       // N*128 fp16 (h)
    __half* bufO  = bufH + (size_t)NN * 128;             // N*128 fp16 (layer1 out)
    float* el     = (float*)(bufO + (size_t)NN * 128);   // N*4
    float* er     = el + NN * 4;                         // N*4
    int* deg      = (int*)(er + NN * 4);                 // N
    int* rowptr   = deg + NN;                            // N+2 (padded even)
    int* csr_src  = rowptr + NN + 2;                     // E
    int2* ebuf    = (int2*)(csr_src + EE);               // E int2 (8B-aligned)
    int* gcnt     = (int*)(ebuf + EE);                   // NGRP2*NPB
    int* poff     = gcnt + NGRP2 * NPB;                  // NGRP2*NPB
    int* bsum     = poff + NGRP2 * NPB;                  // NBLK
    int* boff     = bsum + NBLK;                         // NBLK
    __half* Wt1   = (__half*)(boff + NBLK);              // 128*128 fp16
    __half* Wt2   = Wt1 + 128 * 128;                     // 128*128 fp16

    const int T = 256;
    int gGemm = (NN + 63) / 64;    // 64 rows per block

    // W pre-transpose/convert + CSR build
    wtrans_k<<<64, T, 0, stream>>>(W1, Wt1);
    wtrans_k<<<64, T, 0, stream>>>(W2, Wt2);
    (void)hipMemsetAsync(deg, 0, NN * sizeof(int), stream);
    partA_k<<<NPB, 512, 0, stream>>>(dst, deg, gcnt);
    pscan_k<<<1, 1024, 0, stream>>>(gcnt, poff);
    partB_k<<<NPB, 512, 0, stream>>>(src, dst, poff, ebuf);
    blocksum_k<<<NBLK, T, 0, stream>>>(deg, bsum);
    bscan_k<<<1, 128, 0, stream>>>(bsum, boff, rowptr);
    scanout_k<<<NBLK, T, 0, stream>>>(deg, boff, rowptr);
    partC_k<<<NGRP2, 512, 0, stream>>>(ebuf, poff, rowptr, csr_src);

    // layer 1
    gemm_el_k<0><<<gGemm, T, 0, stream>>>(x, Wt1, al1, ar1, bufH, el, er);
    gat_agg_k<0><<<NN, 64, 0, stream>>>(rowptr, csr_src, el, er, bufH, b1, bufO,
                                        nullptr, nullptr);
    // layer 2 (classifier fused into aggregation epilogue)
    gemm_el_k<1><<<gGemm, T, 0, stream>>>(bufO, Wt2, al2, ar2, bufH, el, er);
    gat_agg_k<1><<<NN, 64, 0, stream>>>(rowptr, csr_src, el, er, bufH, b2, out,
                                        Wf, bf);
}

// Round 16
// 230.240 us; speedup vs baseline: 1.4837x; 1.3427x over previous
//
#include <hip/hip_runtime.h>
#include <hip/hip_fp16.h>

#define NN 100000
#define EE 1600000
#define NPB 256                      // partition blocks
#define EPB (EE / NPB)               // 6250 edges per partition block
#define NGRP2 200                    // dst ranges (counting-sort blocks)
#define GR2 (NN / NGRP2)             // 500 nodes per range
#define CCAP 10240                   // LDS sort capacity (mean 8000, +25 sigma)
#define PSB 50                       // pscan blocks (51200 / 1024)

typedef _Float16 f16x8 __attribute__((ext_vector_type(8)));
typedef float f32x4 __attribute__((ext_vector_type(4)));

// ---------- W pre-transpose + fp16 convert: Wt[n][k] = (half)W[k][n] ----------
__global__ __launch_bounds__(256) void wtrans_k(const float* __restrict__ W,
                                                __half* __restrict__ Wt) {
    int t = blockIdx.x * 256 + threadIdx.x;  // 0..16383
    int k = t >> 7, n = t & 127;
    Wt[n * 128 + k] = __float2half(W[k * 128 + n]);
}

// ---------- MFMA GEMM (Nx128)@(128x128), fp16 in/out, fused el/er ----------
template <int INHALF>
__global__ __launch_bounds__(256) void gemm_el_k(const void* __restrict__ Xv,
                                                 const __half* __restrict__ Wt,
                                                 const float* __restrict__ al,
                                                 const float* __restrict__ ar,
                                                 __half* __restrict__ Hout,
                                                 float* __restrict__ el,
                                                 float* __restrict__ er) {
    __shared__ alignas(16) unsigned short Xs[64 * 128];
    __shared__ alignas(16) unsigned short Ws[128 * 128];
    int t = threadIdx.x;
    int row0 = blockIdx.x * 64;

    // stage Wt -> Ws (2048 x 16B chunks)
    {
        const uint4* g = (const uint4*)Wt;
#pragma unroll
        for (int j = 0; j < 8; ++j) {
            int c = j * 256 + t;
            uint4 v = g[c];
            int n = c >> 4, kb = (c & 15) << 4;
            *(uint4*)((char*)Ws + n * 256 + (kb ^ ((n & 7) << 4))) = v;
        }
    }
    // stage X -> Xs (1024 x 16B fp16 chunks), fp32->fp16 convert if !INHALF
#pragma unroll
    for (int j = 0; j < 4; ++j) {
        int c = j * 256 + t;
        int row = c >> 4, kb = (c & 15) << 4;
        int grow = row0 + row; if (grow >= NN) grow = NN - 1;
        uint4 pk;
        if (INHALF) {
            pk = ((const uint4*)Xv)[(size_t)grow * 16 + (c & 15)];
        } else {
            const float4* xp = (const float4*)Xv + (size_t)grow * 32 + (c & 15) * 2;
            float4 v0 = xp[0], v1 = xp[1];
            __half2 h01 = __floats2half2_rn(v0.x, v0.y);
            __half2 h23 = __floats2half2_rn(v0.z, v0.w);
            __half2 h45 = __floats2half2_rn(v1.x, v1.y);
            __half2 h67 = __floats2half2_rn(v1.z, v1.w);
            pk = make_uint4(__builtin_bit_cast(unsigned, h01),
                            __builtin_bit_cast(unsigned, h23),
                            __builtin_bit_cast(unsigned, h45),
                            __builtin_bit_cast(unsigned, h67));
        }
        *(uint4*)((char*)Xs + row * 256 + (kb ^ ((row & 7) << 4))) = pk;
    }
    __syncthreads();

    int w = t >> 6, lane = t & 63;
    int lr = lane & 15, lg = lane >> 4;
    int arow = w * 16 + lr;

    f32x4 acc[8] = {};
#pragma unroll
    for (int ks = 0; ks < 4; ++ks) {
        int kb = ks * 64 + lg * 16;
        f16x8 a = *(const f16x8*)((char*)Xs + arow * 256 + (kb ^ ((arow & 7) << 4)));
#pragma unroll
        for (int ct = 0; ct < 8; ++ct) {
            int brow = ct * 16 + lr;
            f16x8 b = *(const f16x8*)((char*)Ws + brow * 256 + (kb ^ ((brow & 7) << 4)));
            acc[ct] = __builtin_amdgcn_mfma_f32_16x16x32_f16(a, b, acc[ct], 0, 0, 0);
        }
    }

    // ---- store h (fp16) : lane holds C[lg*4+r][ct*16+lr] ----
#pragma unroll
    for (int r = 0; r < 4; ++r) {
        int grow = row0 + w * 16 + lg * 4 + r;
        if (grow < NN) {
            __half* hp = Hout + (size_t)grow * 128 + lr;
#pragma unroll
            for (int ct = 0; ct < 8; ++ct)
                hp[ct * 16] = __float2half(acc[ct][r]);
        }
    }
    // ---- fused el/er from fp32 accumulators ----
    float alv[8], arv[8];
#pragma unroll
    for (int ct = 0; ct < 8; ++ct) {
        alv[ct] = al[ct * 16 + lr];
        arv[ct] = ar[ct * 16 + lr];
    }
#pragma unroll
    for (int r = 0; r < 4; ++r) {
        int grow = row0 + w * 16 + lg * 4 + r;
#pragma unroll
        for (int hd = 0; hd < 4; ++hd) {
            float pl = acc[2 * hd][r] * alv[2 * hd] + acc[2 * hd + 1][r] * alv[2 * hd + 1];
            float pr = acc[2 * hd][r] * arv[2 * hd] + acc[2 * hd + 1][r] * arv[2 * hd + 1];
#pragma unroll
            for (int off = 1; off < 16; off <<= 1) {
                pl += __shfl_xor(pl, off, 64);
                pr += __shfl_xor(pr, off, 64);
            }
            if (lr == 0 && grow < NN) {
                el[grow * 4 + hd] = pl;
                er[grow * 4 + hd] = pr;
            }
        }
    }
}

// ---------------- CSR build: partition + LDS counting sort ----------------
// Pass A: per-block x per-range histogram (LDS only, no global atomics).
__global__ __launch_bounds__(512) void partA_k(const int* __restrict__ dst,
                                               int* __restrict__ gcnt) {
    __shared__ int cnt[NGRP2];
    int b = blockIdx.x, t = threadIdx.x;
    for (int i = t; i < NGRP2; i += 512) cnt[i] = 0;
    __syncthreads();
    int e_beg = b * EPB;
    for (int e = e_beg + t; e < e_beg + EPB; e += 512)
        atomicAdd(&cnt[dst[e] / GR2], 1);
    __syncthreads();
    for (int i = t; i < NGRP2; i += 512) gcnt[i * NPB + b] = cnt[i];
}

// Hierarchical exclusive scan of gcnt (NGRP2*NPB = 51200 = PSB*1024, g-major).
__global__ __launch_bounds__(1024) void psumA_k(const int* __restrict__ gcnt,
                                                int* __restrict__ psum) {
    __shared__ int sh[1024];
    int b = blockIdx.x, t = threadIdx.x;
    sh[t] = gcnt[b * 1024 + t];
    __syncthreads();
    for (int off = 512; off; off >>= 1) {
        if (t < off) sh[t] += sh[t + off];
        __syncthreads();
    }
    if (t == 0) psum[b] = sh[0];
}

__global__ __launch_bounds__(64) void psumB_k(const int* __restrict__ psum,
                                              int* __restrict__ poffb,
                                              int* __restrict__ rowptr) {
    __shared__ int sh[64];
    int t = threadIdx.x;
    int v = (t < PSB) ? psum[t] : 0;
    sh[t] = v;
    __syncthreads();
    for (int off = 1; off < 64; off <<= 1) {
        int u = (t >= off) ? sh[t - off] : 0;
        __syncthreads();
        sh[t] += u;
        __syncthreads();
    }
    if (t < PSB) poffb[t] = sh[t] - v;
    if (t == 0) rowptr[NN] = EE;
}

__global__ __launch_bounds__(1024) void psumC_k(const int* __restrict__ gcnt,
                                                const int* __restrict__ poffb,
                                                int* __restrict__ poff) {
    __shared__ int sh[1024];
    int b = blockIdx.x, t = threadIdx.x;
    int v = gcnt[b * 1024 + t];
    sh[t] = v;
    __syncthreads();
    for (int off = 1; off < 1024; off <<= 1) {
        int u = (t >= off) ? sh[t - off] : 0;
        __syncthreads();
        sh[t] += u;
        __syncthreads();
    }
    poff[b * 1024 + t] = sh[t] - v + poffb[b];
}

// Pass B: partition edges into per-range contiguous (src,dst) buffers.
__global__ __launch_bounds__(512) void partB_k(const int* __restrict__ src,
                                               const int* __restrict__ dst,
                                               const int* __restrict__ poff,
                                               int2* __restrict__ ebuf) {
    __shared__ int cur[NGRP2];
    int b = blockIdx.x, t = threadIdx.x;
    for (int i = t; i < NGRP2; i += 512) cur[i] = poff[i * NPB + b];
    __syncthreads();
    int e_beg = b * EPB;
    for (int e = e_beg + t; e < e_beg + EPB; e += 512) {
        int d = dst[e], s = src[e];
        int p = atomicAdd(&cur[d / GR2], 1);
        ebuf[p] = make_int2(s, d);
    }
}

// Pass C: per-range LDS counting sort; derives rowptr locally (no global deg).
__global__ __launch_bounds__(512) void partC_k(const int2* __restrict__ ebuf,
                                               const int* __restrict__ poff,
                                               int* __restrict__ rowptr,
                                               int* __restrict__ csr_src) {
    __shared__ int lsrc[CCAP];
    __shared__ int ldeg[512];
    __shared__ int ssc[512];
    __shared__ int lcur[512];
    int g = blockIdx.x, t = threadIdx.x;
    int nbase = g * GR2;
    int beg = poff[g * NPB];
    int end = (g == NGRP2 - 1) ? EE : poff[(g + 1) * NPB];
    ldeg[t] = 0;
    __syncthreads();
    for (int e = beg + t; e < end; e += 512) {
        int2 sd = ebuf[e];
        atomicAdd(&ldeg[sd.y - nbase], 1);
    }
    __syncthreads();
    // exclusive scan of ldeg[0..512)
    int v = ldeg[t];
    ssc[t] = v;
    __syncthreads();
    for (int off = 1; off < 512; off <<= 1) {
        int u = (t >= off) ? ssc[t - off] : 0;
        __syncthreads();
        ssc[t] += u;
        __syncthreads();
    }
    int ex = ssc[t] - v;
    lcur[t] = ex;
    if (t < GR2) rowptr[nbase + t] = beg + ex;
    __syncthreads();
    for (int e = beg + t; e < end; e += 512) {
        int2 sd = ebuf[e];
        int p = atomicAdd(&lcur[sd.y - nbase], 1);
        if (p < CCAP) lsrc[p] = sd.x;
    }
    __syncthreads();
    int len = end - beg; if (len > CCAP) len = CCAP;
    for (int i = t; i < len; i += 512) csr_src[beg + i] = lsrc[i];
}

// ---------- fused per-node softmax + aggregation ----------
#define BC16(x, I) __uint_as_float(__builtin_amdgcn_ds_swizzle( \
    __float_as_uint(x), ((I) << 5) | 0x10))

#define AGG_STEP(av, hvp, I)                      \
    {                                             \
        float ai = BC16(av, I);                   \
        float2 f = __half22float2((hvp)[I]);      \
        acc0 = fmaf(ai, f.x, acc0);               \
        acc1 = fmaf(ai, f.y, acc1);               \
    }

#define AGG16(av, hvp)                                                       \
    AGG_STEP(av, hvp, 0)  AGG_STEP(av, hvp, 1)  AGG_STEP(av, hvp, 2)         \
    AGG_STEP(av, hvp, 3)  AGG_STEP(av, hvp, 4)  AGG_STEP(av, hvp, 5)         \
    AGG_STEP(av, hvp, 6)  AGG_STEP(av, hvp, 7)  AGG_STEP(av, hvp, 8)         \
    AGG_STEP(av, hvp, 9)  AGG_STEP(av, hvp, 10) AGG_STEP(av, hvp, 11)        \
    AGG_STEP(av, hvp, 12) AGG_STEP(av, hvp, 13) AGG_STEP(av, hvp, 14)        \
    AGG_STEP(av, hvp, 15)

template <int FINAL>
__global__ __launch_bounds__(64) void gat_agg_k(const int* __restrict__ rowptr,
                                                const int* __restrict__ csr_src,
                                                const float* __restrict__ el,
                                                const float* __restrict__ er,
                                                const __half* __restrict__ h,
                                                const float* __restrict__ bias,
                                                void* __restrict__ outv,
                                                const float* __restrict__ Wf,
                                                const float* __restrict__ bf) {
    int wave = blockIdx.x;
    int lane = threadIdx.x;
    int row = rowptr[wave], end = rowptr[wave + 1];
    int hd = lane >> 4, sub = lane & 15;
    float erd = er[wave * 4 + hd];
    const __half2* hbase = (const __half2*)h + lane;  // + si*64 per gather

    float dpart = 0.f, acc0 = 0.f, acc1 = 0.f;
    for (int base = row; base < end; base += 32) {
        int c = end - base;
        int s0 = csr_src[base + (sub < c ? sub : 0)];
        float a0 = 0.f;
        {
            float v = el[s0 * 4 + hd] + erd;
            v = (v >= 0.f) ? v : 0.2f * v;
            if (sub < c) a0 = __expf(v);
        }
        if (c > 16) {
            int i1 = 16 + sub;
            int s1 = csr_src[base + (i1 < c ? i1 : 0)];
            float a1 = 0.f;
            {
                float v = el[s1 * 4 + hd] + erd;
                v = (v >= 0.f) ? v : 0.2f * v;
                if (i1 < c) a1 = __expf(v);
            }
            dpart += a0 + a1;
            __half2 hv[32];
#pragma unroll
            for (int i = 0; i < 16; ++i) {
                int si = __builtin_amdgcn_readlane(s0, i);
                hv[i] = hbase[si * 64];
            }
#pragma unroll
            for (int i = 0; i < 16; ++i) {
                int si = __builtin_amdgcn_readlane(s1, i);
                hv[16 + i] = hbase[si * 64];
            }
            AGG16(a0, hv)
            AGG16(a1, (hv + 16))
        } else {
            dpart += a0;
            __half2 hv[16];
#pragma unroll
            for (int i = 0; i < 16; ++i) {
                int si = __builtin_amdgcn_readlane(s0, i);
                hv[i] = hbase[si * 64];
            }
            AGG16(a0, hv)
        }
    }
    float denom = dpart;
#pragma unroll
    for (int off = 1; off < 16; off <<= 1) denom += __shfl_xor(denom, off, 64);
    float inv = 1.f / fmaxf(denom, 1e-9f);
    float2 bv = *(const float2*)&bias[lane * 2];
    float o0 = acc0 * inv + bv.x;
    float o1 = acc1 * inv + bv.y;

    if (FINAL) {
        float* out = (float*)outv;
        float4 wf = *(const float4*)&Wf[lane * 4];
        float c0 = o0 * wf.x + o1 * wf.z;
        float c1 = o0 * wf.y + o1 * wf.w;
#pragma unroll
        for (int off = 1; off < 64; off <<= 1) {
            c0 += __shfl_xor(c0, off, 64);
            c1 += __shfl_xor(c1, off, 64);
        }
        if (lane == 0) {
            float2 res = make_float2(c0 + bf[0], c1 + bf[1]);
            *(float2*)&out[(size_t)wave * 2] = res;
        }
    } else {
        __half* out = (__half*)outv;
        *(__half2*)&out[(size_t)wave * 128 + lane * 2] = __floats2half2_rn(o0, o1);
    }
}

extern "C" void kernel_launch(void* const* d_in, const int* in_sizes, int n_in,
                              void* d_out, int out_size, void* d_ws, size_t ws_size,
                              hipStream_t stream) {
    const float* x   = (const float*)d_in[0];
    const int*   src = (const int*)d_in[1];
    const int*   dst = (const int*)d_in[2];
    const float* W1  = (const float*)d_in[3];
    const float* al1 = (const float*)d_in[4];
    const float* ar1 = (const float*)d_in[5];
    const float* b1  = (const float*)d_in[6];
    const float* W2  = (const float*)d_in[7];
    const float* al2 = (const float*)d_in[8];
    const float* ar2 = (const float*)d_in[9];
    const float* b2  = (const float*)d_in[10];
    const float* Wf  = (const float*)d_in[11];
    const float* bf  = (const float*)d_in[12];
    float* out = (float*)d_out;

    __half* bufH  = (__half*)d_ws;                       // N*128 fp16 (h)
    __half* bufO  = bufH + (size_t)NN * 128;             // N*128 fp16 (layer1 out)
    float* el     = (float*)(bufO + (size_t)NN * 128);   // N*4
    float* er     = el + NN * 4;                         // N*4
    int* rowptr   = (int*)(er + NN * 4);                 // N+2 (padded even)
    int* csr_src  = rowptr + NN + 2;                     // E
    int2* ebuf    = (int2*)(csr_src + EE);               // E int2 (8B-aligned)
    int* gcnt     = (int*)(ebuf + EE);                   // NGRP2*NPB
    int* poff     = gcnt + NGRP2 * NPB;                  // NGRP2*NPB
    int* psum     = poff + NGRP2 * NPB;                  // PSB
    int* poffb    = psum + PSB;                          // PSB
    __half* Wt1   = (__half*)(poffb + PSB);              // 128*128 fp16
    __half* Wt2   = Wt1 + 128 * 128;                     // 128*128 fp16

    const int T = 256;
    int gGemm = (NN + 63) / 64;    // 64 rows per block

    // W pre-transpose/convert + CSR build
    wtrans_k<<<64, T, 0, stream>>>(W1, Wt1);
    wtrans_k<<<64, T, 0, stream>>>(W2, Wt2);
    partA_k<<<NPB, 512, 0, stream>>>(dst, gcnt);
    psumA_k<<<PSB, 1024, 0, stream>>>(gcnt, psum);
    psumB_k<<<1, 64, 0, stream>>>(psum, poffb, rowptr);
    psumC_k<<<PSB, 1024, 0, stream>>>(gcnt, poffb, poff);
    partB_k<<<NPB, 512, 0, stream>>>(src, dst, poff, ebuf);
    partC_k<<<NGRP2, 512, 0, stream>>>(ebuf, poff, rowptr, csr_src);

    // layer 1
    gemm_el_k<0><<<gGemm, T, 0, stream>>>(x, Wt1, al1, ar1, bufH, el, er);
    gat_agg_k<0><<<NN, 64, 0, stream>>>(rowptr, csr_src, el, er, bufH, b1, bufO,
                                        nullptr, nullptr);
    // layer 2 (classifier fused into aggregation epilogue)
    gemm_el_k<1><<<gGemm, T, 0, stream>>>(bufO, Wt2, al2, ar2, bufH, el, er);
    gat_agg_k<1><<<NN, 64, 0, stream>>>(rowptr, csr_src, el, er, bufH, b2, out,
                                        Wf, bf);
}

// Round 17
// 221.239 us; speedup vs baseline: 1.5440x; 1.0407x over previous
//
#include <hip/hip_runtime.h>
#include <hip/hip_fp16.h>

#define NN 100000
#define EE 1600000
#define NPB 256                      // partition blocks
#define EPB (EE / NPB)               // 6250 edges per partition block
#define NGRP2 200                    // dst ranges (counting-sort blocks)
#define GR2 (NN / NGRP2)             // 500 nodes per range
#define CCAP 10240                   // LDS sort capacity (mean 8000, +25 sigma)
#define PSB 50                       // pscan blocks (51200 / 1024)

typedef _Float16 f16x8 __attribute__((ext_vector_type(8)));
typedef float f32x4 __attribute__((ext_vector_type(4)));

// ---------- W pre-transpose + fp16 convert (both layers in one launch) ----------
__global__ __launch_bounds__(256) void wtrans_k(const float* __restrict__ W1,
                                                const float* __restrict__ W2,
                                                __half* __restrict__ Wt1,
                                                __half* __restrict__ Wt2) {
    int b = blockIdx.x;
    const float* W = (b & 1) ? W2 : W1;
    __half* Wt = (b & 1) ? Wt2 : Wt1;
    int t = (b >> 1) * 256 + threadIdx.x;  // 0..16383
    int k = t >> 7, n = t & 127;
    Wt[n * 128 + k] = __float2half(W[k * 128 + n]);
}

// ---------- MFMA GEMM (Nx128)@(128x128), fp16 in/out, fused el/er ----------
// SWAPPED operands: D = Wt_tile * X_tile^T -> lane holds X-row j=lane&15 and
// 4 CONSECUTIVE features (ct*16 + lg*4 + r). Vector h-stores + cheap el/er.
template <int INHALF>
__global__ __launch_bounds__(256) void gemm_el_k(const void* __restrict__ Xv,
                                                 const __half* __restrict__ Wt,
                                                 const float* __restrict__ al,
                                                 const float* __restrict__ ar,
                                                 __half* __restrict__ Hout,
                                                 float* __restrict__ el,
                                                 float* __restrict__ er) {
    __shared__ alignas(16) unsigned short Xs[64 * 128];
    __shared__ alignas(16) unsigned short Ws[128 * 128];
    int t = threadIdx.x;
    int row0 = blockIdx.x * 64;

    // stage Wt -> Ws (2048 x 16B chunks)
    {
        const uint4* g = (const uint4*)Wt;
#pragma unroll
        for (int j = 0; j < 8; ++j) {
            int c = j * 256 + t;
            uint4 v = g[c];
            int n = c >> 4, kb = (c & 15) << 4;
            *(uint4*)((char*)Ws + n * 256 + (kb ^ ((n & 7) << 4))) = v;
        }
    }
    // stage X -> Xs (1024 x 16B fp16 chunks), fp32->fp16 convert if !INHALF
#pragma unroll
    for (int j = 0; j < 4; ++j) {
        int c = j * 256 + t;
        int row = c >> 4, kb = (c & 15) << 4;
        int grow = row0 + row; if (grow >= NN) grow = NN - 1;
        uint4 pk;
        if (INHALF) {
            pk = ((const uint4*)Xv)[(size_t)grow * 16 + (c & 15)];
        } else {
            const float4* xp = (const float4*)Xv + (size_t)grow * 32 + (c & 15) * 2;
            float4 v0 = xp[0], v1 = xp[1];
            __half2 h01 = __floats2half2_rn(v0.x, v0.y);
            __half2 h23 = __floats2half2_rn(v0.z, v0.w);
            __half2 h45 = __floats2half2_rn(v1.x, v1.y);
            __half2 h67 = __floats2half2_rn(v1.z, v1.w);
            pk = make_uint4(__builtin_bit_cast(unsigned, h01),
                            __builtin_bit_cast(unsigned, h23),
                            __builtin_bit_cast(unsigned, h45),
                            __builtin_bit_cast(unsigned, h67));
        }
        *(uint4*)((char*)Xs + row * 256 + (kb ^ ((row & 7) << 4))) = pk;
    }
    __syncthreads();

    int w = t >> 6, lane = t & 63;
    int lr = lane & 15, lg = lane >> 4;
    int xrow = w * 16 + lr;

    f32x4 acc[8] = {};
#pragma unroll
    for (int ks = 0; ks < 4; ++ks) {
        int kb = ks * 64 + lg * 16;  // BYTES: k-slice (lane>>4)*8 halves
        f16x8 b = *(const f16x8*)((char*)Xs + xrow * 256 + (kb ^ ((xrow & 7) << 4)));
#pragma unroll
        for (int ct = 0; ct < 8; ++ct) {
            int wrow = ct * 16 + lr;
            f16x8 a = *(const f16x8*)((char*)Ws + wrow * 256 + (kb ^ ((wrow & 7) << 4)));
            acc[ct] = __builtin_amdgcn_mfma_f32_16x16x32_f16(a, b, acc[ct], 0, 0, 0);
        }
    }

    // lane holds h[row0+w*16+lr][ct*16+lg*4 + 0..3] (4 consecutive features)
    int grow = row0 + w * 16 + lr;
    bool valid = grow < NN;
    if (valid) {
        __half* hp = Hout + (size_t)grow * 128 + lg * 4;
#pragma unroll
        for (int ct = 0; ct < 8; ++ct) {
            __half2 p0 = __floats2half2_rn(acc[ct][0], acc[ct][1]);
            __half2 p1 = __floats2half2_rn(acc[ct][2], acc[ct][3]);
            uint2 pk = make_uint2(__builtin_bit_cast(unsigned, p0),
                                  __builtin_bit_cast(unsigned, p1));
            *(uint2*)(hp + ct * 16) = pk;
        }
    }
    // el/er: per-lane partials over its 32 features, reduce across lg (xor 16,32)
    float pl[4] = {}, pr[4] = {};
#pragma unroll
    for (int ct = 0; ct < 8; ++ct) {
        int hd = ct >> 1;
        float4 a_l = *(const float4*)&al[ct * 16 + lg * 4];
        float4 a_r = *(const float4*)&ar[ct * 16 + lg * 4];
        pl[hd] += acc[ct][0] * a_l.x + acc[ct][1] * a_l.y +
                  acc[ct][2] * a_l.z + acc[ct][3] * a_l.w;
        pr[hd] += acc[ct][0] * a_r.x + acc[ct][1] * a_r.y +
                  acc[ct][2] * a_r.z + acc[ct][3] * a_r.w;
    }
#pragma unroll
    for (int hd = 0; hd < 4; ++hd) {
        pl[hd] += __shfl_xor(pl[hd], 16, 64);
        pl[hd] += __shfl_xor(pl[hd], 32, 64);
        pr[hd] += __shfl_xor(pr[hd], 16, 64);
        pr[hd] += __shfl_xor(pr[hd], 32, 64);
    }
    if (lg == 0 && valid) {
        *(float4*)&el[grow * 4] = make_float4(pl[0], pl[1], pl[2], pl[3]);
        *(float4*)&er[grow * 4] = make_float4(pr[0], pr[1], pr[2], pr[3]);
    }
}

// ---------------- CSR build: partition + LDS counting sort ----------------
// Pass A: per-block x per-range histogram (LDS only).
__global__ __launch_bounds__(512) void partA_k(const int* __restrict__ dst,
                                               int* __restrict__ gcnt) {
    __shared__ int cnt[NGRP2];
    int b = blockIdx.x, t = threadIdx.x;
    for (int i = t; i < NGRP2; i += 512) cnt[i] = 0;
    __syncthreads();
    int e_beg = b * EPB;
    for (int e = e_beg + t; e < e_beg + EPB; e += 512)
        atomicAdd(&cnt[dst[e] / GR2], 1);
    __syncthreads();
    for (int i = t; i < NGRP2; i += 512) gcnt[i * NPB + b] = cnt[i];
}

// Hierarchical exclusive scan of gcnt (51200 = PSB*1024, g-major).
__global__ __launch_bounds__(1024) void psumA_k(const int* __restrict__ gcnt,
                                                int* __restrict__ psum) {
    __shared__ int sh[1024];
    int b = blockIdx.x, t = threadIdx.x;
    sh[t] = gcnt[b * 1024 + t];
    __syncthreads();
    for (int off = 512; off; off >>= 1) {
        if (t < off) sh[t] += sh[t + off];
        __syncthreads();
    }
    if (t == 0) psum[b] = sh[0];
}

__global__ __launch_bounds__(64) void psumB_k(const int* __restrict__ psum,
                                              int* __restrict__ poffb,
                                              int* __restrict__ rowptr) {
    __shared__ int sh[64];
    int t = threadIdx.x;
    int v = (t < PSB) ? psum[t] : 0;
    sh[t] = v;
    __syncthreads();
    for (int off = 1; off < 64; off <<= 1) {
        int u = (t >= off) ? sh[t - off] : 0;
        __syncthreads();
        sh[t] += u;
        __syncthreads();
    }
    if (t < PSB) poffb[t] = sh[t] - v;
    if (t == 0) rowptr[NN] = EE;
}

__global__ __launch_bounds__(1024) void psumC_k(const int* __restrict__ gcnt,
                                                const int* __restrict__ poffb,
                                                int* __restrict__ poff) {
    __shared__ int sh[1024];
    int b = blockIdx.x, t = threadIdx.x;
    int v = gcnt[b * 1024 + t];
    sh[t] = v;
    __syncthreads();
    for (int off = 1; off < 1024; off <<= 1) {
        int u = (t >= off) ? sh[t - off] : 0;
        __syncthreads();
        sh[t] += u;
        __syncthreads();
    }
    poff[b * 1024 + t] = sh[t] - v + poffb[b];
}

// Pass B: partition edges; PACKED 4B entries: src (17b) | (d%GR2)<<17 (9b).
__global__ __launch_bounds__(512) void partB_k(const int* __restrict__ src,
                                               const int* __restrict__ dst,
                                               const int* __restrict__ poff,
                                               int* __restrict__ ebuf) {
    __shared__ int cur[NGRP2];
    int b = blockIdx.x, t = threadIdx.x;
    for (int i = t; i < NGRP2; i += 512) cur[i] = poff[i * NPB + b];
    __syncthreads();
    int e_beg = b * EPB;
    for (int e = e_beg + t; e < e_beg + EPB; e += 512) {
        int d = dst[e], s = src[e];
        int g = d / GR2;
        int p = atomicAdd(&cur[g], 1);
        ebuf[p] = s | ((d - g * GR2) << 17);
    }
}

// Pass C: per-range LDS counting sort; derives rowptr locally.
__global__ __launch_bounds__(512) void partC_k(const int* __restrict__ ebuf,
                                               const int* __restrict__ poff,
                                               int* __restrict__ rowptr,
                                               int* __restrict__ csr_src) {
    __shared__ int lsrc[CCAP];
    __shared__ int ldeg[512];
    __shared__ int ssc[512];
    __shared__ int lcur[512];
    int g = blockIdx.x, t = threadIdx.x;
    int nbase = g * GR2;
    int beg = poff[g * NPB];
    int end = (g == NGRP2 - 1) ? EE : poff[(g + 1) * NPB];
    ldeg[t] = 0;
    __syncthreads();
    for (int e = beg + t; e < end; e += 512)
        atomicAdd(&ldeg[ebuf[e] >> 17], 1);
    __syncthreads();
    int v = ldeg[t];
    ssc[t] = v;
    __syncthreads();
    for (int off = 1; off < 512; off <<= 1) {
        int u = (t >= off) ? ssc[t - off] : 0;
        __syncthreads();
        ssc[t] += u;
        __syncthreads();
    }
    int ex = ssc[t] - v;
    lcur[t] = ex;
    if (t < GR2) rowptr[nbase + t] = beg + ex;
    __syncthreads();
    for (int e = beg + t; e < end; e += 512) {
        int pk = ebuf[e];
        int p = atomicAdd(&lcur[pk >> 17], 1);
        if (p < CCAP) lsrc[p] = pk & 0x1FFFF;
    }
    __syncthreads();
    int len = end - beg; if (len > CCAP) len = CCAP;
    for (int i = t; i < len; i += 512) csr_src[beg + i] = lsrc[i];
}

// ---------- fused per-node softmax + aggregation ----------
#define BC16(x, I) __uint_as_float(__builtin_amdgcn_ds_swizzle( \
    __float_as_uint(x), ((I) << 5) | 0x10))

#define AGG_STEP(av, hvp, I)                      \
    {                                             \
        float ai = BC16(av, I);                   \
        float2 f = __half22float2((hvp)[I]);      \
        acc0 = fmaf(ai, f.x, acc0);               \
        acc1 = fmaf(ai, f.y, acc1);               \
    }

#define AGG16(av, hvp)                                                       \
    AGG_STEP(av, hvp, 0)  AGG_STEP(av, hvp, 1)  AGG_STEP(av, hvp, 2)         \
    AGG_STEP(av, hvp, 3)  AGG_STEP(av, hvp, 4)  AGG_STEP(av, hvp, 5)         \
    AGG_STEP(av, hvp, 6)  AGG_STEP(av, hvp, 7)  AGG_STEP(av, hvp, 8)         \
    AGG_STEP(av, hvp, 9)  AGG_STEP(av, hvp, 10) AGG_STEP(av, hvp, 11)        \
    AGG_STEP(av, hvp, 12) AGG_STEP(av, hvp, 13) AGG_STEP(av, hvp, 14)        \
    AGG_STEP(av, hvp, 15)

template <int FINAL>
__global__ __launch_bounds__(64) void gat_agg_k(const int* __restrict__ rowptr,
                                                const int* __restrict__ csr_src,
                                                const float* __restrict__ el,
                                                const float* __restrict__ er,
                                                const __half* __restrict__ h,
                                                const float* __restrict__ bias,
                                                void* __restrict__ outv,
                                                const float* __restrict__ Wf,
                                                const float* __restrict__ bf) {
    int wave = blockIdx.x;
    int lane = threadIdx.x;
    int row = rowptr[wave], end = rowptr[wave + 1];
    int hd = lane >> 4, sub = lane & 15;
    float erd = er[wave * 4 + hd];
    const __half2* hbase = (const __half2*)h + lane;  // + si*64 per gather

    float dpart = 0.f, acc0 = 0.f, acc1 = 0.f;
    for (int base = row; base < end; base += 32) {
        int c = end - base;
        int s0 = csr_src[base + (sub < c ? sub : 0)];
        float a0 = 0.f;
        {
            float v = el[s0 * 4 + hd] + erd;
            v = (v >= 0.f) ? v : 0.2f * v;
            if (sub < c) a0 = __expf(v);
        }
        if (c > 16) {
            int i1 = 16 + sub;
            int s1 = csr_src[base + (i1 < c ? i1 : 0)];
            float a1 = 0.f;
            {
                float v = el[s1 * 4 + hd] + erd;
                v = (v >= 0.f) ? v : 0.2f * v;
                if (i1 < c) a1 = __expf(v);
            }
            dpart += a0 + a1;
            __half2 hv[32];
#pragma unroll
            for (int i = 0; i < 16; ++i) {
                int si = __builtin_amdgcn_readlane(s0, i);
                hv[i] = hbase[si * 64];
            }
#pragma unroll
            for (int i = 0; i < 16; ++i) {
                int si = __builtin_amdgcn_readlane(s1, i);
                hv[16 + i] = hbase[si * 64];
            }
            AGG16(a0, hv)
            AGG16(a1, (hv + 16))
        } else {
            dpart += a0;
            __half2 hv[16];
#pragma unroll
            for (int i = 0; i < 16; ++i) {
                int si = __builtin_amdgcn_readlane(s0, i);
                hv[i] = hbase[si * 64];
            }
            AGG16(a0, hv)
        }
    }
    float denom = dpart;
#pragma unroll
    for (int off = 1; off < 16; off <<= 1) denom += __shfl_xor(denom, off, 64);
    float inv = 1.f / fmaxf(denom, 1e-9f);
    float2 bv = *(const float2*)&bias[lane * 2];
    float o0 = acc0 * inv + bv.x;
    float o1 = acc1 * inv + bv.y;

    if (FINAL) {
        float* out = (float*)outv;
        float4 wf = *(const float4*)&Wf[lane * 4];
        float c0 = o0 * wf.x + o1 * wf.z;
        float c1 = o0 * wf.y + o1 * wf.w;
#pragma unroll
        for (int off = 1; off < 64; off <<= 1) {
            c0 += __shfl_xor(c0, off, 64);
            c1 += __shfl_xor(c1, off, 64);
        }
        if (lane == 0) {
            float2 res = make_float2(c0 + bf[0], c1 + bf[1]);
            *(float2*)&out[(size_t)wave * 2] = res;
        }
    } else {
        __half* out = (__half*)outv;
        *(__half2*)&out[(size_t)wave * 128 + lane * 2] = __floats2half2_rn(o0, o1);
    }
}

extern "C" void kernel_launch(void* const* d_in, const int* in_sizes, int n_in,
                              void* d_out, int out_size, void* d_ws, size_t ws_size,
                              hipStream_t stream) {
    const float* x   = (const float*)d_in[0];
    const int*   src = (const int*)d_in[1];
    const int*   dst = (const int*)d_in[2];
    const float* W1  = (const float*)d_in[3];
    const float* al1 = (const float*)d_in[4];
    const float* ar1 = (const float*)d_in[5];
    const float* b1  = (const float*)d_in[6];
    const float* W2  = (const float*)d_in[7];
    const float* al2 = (const float*)d_in[8];
    const float* ar2 = (const float*)d_in[9];
    const float* b2  = (const float*)d_in[10];
    const float* Wf  = (const float*)d_in[11];
    const float* bf  = (const float*)d_in[12];
    float* out = (float*)d_out;

    __half* bufH  = (__half*)d_ws;                       // N*128 fp16 (h)
    __half* bufO  = bufH + (size_t)NN * 128;             // N*128 fp16 (layer1 out)
    float* el     = (float*)(bufO + (size_t)NN * 128);   // N*4
    float* er     = el + NN * 4;                         // N*4
    int* rowptr   = (int*)(er + NN * 4);                 // N+2 (padded even)
    int* csr_src  = rowptr + NN + 2;                     // E
    int* ebuf     = csr_src + EE;                        // E (packed 4B)
    int* gcnt     = ebuf + EE;                           // NGRP2*NPB
    int* poff     = gcnt + NGRP2 * NPB;                  // NGRP2*NPB
    int* psum     = poff + NGRP2 * NPB;                  // PSB
    int* poffb    = psum + PSB;                          // PSB
    __half* Wt1   = (__half*)(poffb + PSB);              // 128*128 fp16
    __half* Wt2   = Wt1 + 128 * 128;                     // 128*128 fp16

    const int T = 256;
    int gGemm = (NN + 63) / 64;    // 64 rows per block

    // W pre-transpose/convert + CSR build
    wtrans_k<<<128, T, 0, stream>>>(W1, W2, Wt1, Wt2);
    partA_k<<<NPB, 512, 0, stream>>>(dst, gcnt);
    psumA_k<<<PSB, 1024, 0, stream>>>(gcnt, psum);
    psumB_k<<<1, 64, 0, stream>>>(psum, poffb, rowptr);
    psumC_k<<<PSB, 1024, 0, stream>>>(gcnt, poffb, poff);
    partB_k<<<NPB, 512, 0, stream>>>(src, dst, poff, ebuf);
    partC_k<<<NGRP2, 512, 0, stream>>>(ebuf, poff, rowptr, csr_src);

    // layer 1
    gemm_el_k<0><<<gGemm, T, 0, stream>>>(x, Wt1, al1, ar1, bufH, el, er);
    gat_agg_k<0><<<NN, 64, 0, stream>>>(rowptr, csr_src, el, er, bufH, b1, bufO,
                                        nullptr, nullptr);
    // layer 2 (classifier fused into aggregation epilogue)
    gemm_el_k<1><<<gGemm, T, 0, stream>>>(bufO, Wt2, al2, ar2, bufH, el, er);
    gat_agg_k<1><<<NN, 64, 0, stream>>>(rowptr, csr_src, el, er, bufH, b2, out,
                                        Wf, bf);
}

// Round 18
// 221.111 us; speedup vs baseline: 1.5449x; 1.0006x over previous
//
#include <hip/hip_runtime.h>
#include <hip/hip_fp16.h>

#define NN 100000
#define EE 1600000
#define NPB 256                      // partition blocks
#define EPB (EE / NPB)               // 6250 edges per partition block
#define NGRP2 200                    // dst ranges (counting-sort blocks)
#define GR2 (NN / NGRP2)             // 500 nodes per range
#define CCAP 10240                   // LDS sort capacity (mean 8000, +25 sigma)
#define PSB 50                       // pscan blocks (51200 / 1024)

typedef _Float16 f16x8 __attribute__((ext_vector_type(8)));
typedef float f32x4 __attribute__((ext_vector_type(4)));

// ---------- W pre-transpose + fp16 convert (both layers in one launch) ----------
__global__ __launch_bounds__(256) void wtrans_k(const float* __restrict__ W1,
                                                const float* __restrict__ W2,
                                                __half* __restrict__ Wt1,
                                                __half* __restrict__ Wt2) {
    int b = blockIdx.x;
    const float* W = (b & 1) ? W2 : W1;
    __half* Wt = (b & 1) ? Wt2 : Wt1;
    int t = (b >> 1) * 256 + threadIdx.x;  // 0..16383
    int k = t >> 7, n = t & 127;
    Wt[n * 128 + k] = __float2half(W[k * 128 + n]);
}

// ---------- MFMA GEMM (Nx128)@(128x128), fp16 in/out, fused el/er ----------
// SWAPPED operands: D = Wt_tile * X_tile^T -> lane holds X-row j=lane&15 and
// 4 CONSECUTIVE features (ct*16 + lg*4 + r). Vector h-stores + cheap el/er.
template <int INHALF>
__global__ __launch_bounds__(256) void gemm_el_k(const void* __restrict__ Xv,
                                                 const __half* __restrict__ Wt,
                                                 const float* __restrict__ al,
                                                 const float* __restrict__ ar,
                                                 __half* __restrict__ Hout,
                                                 float* __restrict__ el,
                                                 float* __restrict__ er) {
    __shared__ alignas(16) unsigned short Xs[64 * 128];
    __shared__ alignas(16) unsigned short Ws[128 * 128];
    int t = threadIdx.x;
    int row0 = blockIdx.x * 64;

    // stage Wt -> Ws (2048 x 16B chunks)
    {
        const uint4* g = (const uint4*)Wt;
#pragma unroll
        for (int j = 0; j < 8; ++j) {
            int c = j * 256 + t;
            uint4 v = g[c];
            int n = c >> 4, kb = (c & 15) << 4;
            *(uint4*)((char*)Ws + n * 256 + (kb ^ ((n & 7) << 4))) = v;
        }
    }
    // stage X -> Xs (1024 x 16B fp16 chunks), fp32->fp16 convert if !INHALF
#pragma unroll
    for (int j = 0; j < 4; ++j) {
        int c = j * 256 + t;
        int row = c >> 4, kb = (c & 15) << 4;
        int grow = row0 + row; if (grow >= NN) grow = NN - 1;
        uint4 pk;
        if (INHALF) {
            pk = ((const uint4*)Xv)[(size_t)grow * 16 + (c & 15)];
        } else {
            const float4* xp = (const float4*)Xv + (size_t)grow * 32 + (c & 15) * 2;
            float4 v0 = xp[0], v1 = xp[1];
            __half2 h01 = __floats2half2_rn(v0.x, v0.y);
            __half2 h23 = __floats2half2_rn(v0.z, v0.w);
            __half2 h45 = __floats2half2_rn(v1.x, v1.y);
            __half2 h67 = __floats2half2_rn(v1.z, v1.w);
            pk = make_uint4(__builtin_bit_cast(unsigned, h01),
                            __builtin_bit_cast(unsigned, h23),
                            __builtin_bit_cast(unsigned, h45),
                            __builtin_bit_cast(unsigned, h67));
        }
        *(uint4*)((char*)Xs + row * 256 + (kb ^ ((row & 7) << 4))) = pk;
    }
    __syncthreads();

    int w = t >> 6, lane = t & 63;
    int lr = lane & 15, lg = lane >> 4;
    int xrow = w * 16 + lr;

    f32x4 acc[8] = {};
#pragma unroll
    for (int ks = 0; ks < 4; ++ks) {
        int kb = ks * 64 + lg * 16;  // BYTES: k-slice (lane>>4)*8 halves
        f16x8 b = *(const f16x8*)((char*)Xs + xrow * 256 + (kb ^ ((xrow & 7) << 4)));
#pragma unroll
        for (int ct = 0; ct < 8; ++ct) {
            int wrow = ct * 16 + lr;
            f16x8 a = *(const f16x8*)((char*)Ws + wrow * 256 + (kb ^ ((wrow & 7) << 4)));
            acc[ct] = __builtin_amdgcn_mfma_f32_16x16x32_f16(a, b, acc[ct], 0, 0, 0);
        }
    }

    // lane holds h[row0+w*16+lr][ct*16+lg*4 + 0..3] (4 consecutive features)
    int grow = row0 + w * 16 + lr;
    bool valid = grow < NN;
    if (valid) {
        __half* hp = Hout + (size_t)grow * 128 + lg * 4;
#pragma unroll
        for (int ct = 0; ct < 8; ++ct) {
            __half2 p0 = __floats2half2_rn(acc[ct][0], acc[ct][1]);
            __half2 p1 = __floats2half2_rn(acc[ct][2], acc[ct][3]);
            uint2 pk = make_uint2(__builtin_bit_cast(unsigned, p0),
                                  __builtin_bit_cast(unsigned, p1));
            *(uint2*)(hp + ct * 16) = pk;
        }
    }
    // el/er: per-lane partials over its 32 features, reduce across lg (xor 16,32)
    float pl[4] = {}, pr[4] = {};
#pragma unroll
    for (int ct = 0; ct < 8; ++ct) {
        int hd = ct >> 1;
        float4 a_l = *(const float4*)&al[ct * 16 + lg * 4];
        float4 a_r = *(const float4*)&ar[ct * 16 + lg * 4];
        pl[hd] += acc[ct][0] * a_l.x + acc[ct][1] * a_l.y +
                  acc[ct][2] * a_l.z + acc[ct][3] * a_l.w;
        pr[hd] += acc[ct][0] * a_r.x + acc[ct][1] * a_r.y +
                  acc[ct][2] * a_r.z + acc[ct][3] * a_r.w;
    }
#pragma unroll
    for (int hd = 0; hd < 4; ++hd) {
        pl[hd] += __shfl_xor(pl[hd], 16, 64);
        pl[hd] += __shfl_xor(pl[hd], 32, 64);
        pr[hd] += __shfl_xor(pr[hd], 16, 64);
        pr[hd] += __shfl_xor(pr[hd], 32, 64);
    }
    if (lg == 0 && valid) {
        *(float4*)&el[grow * 4] = make_float4(pl[0], pl[1], pl[2], pl[3]);
        *(float4*)&er[grow * 4] = make_float4(pr[0], pr[1], pr[2], pr[3]);
    }
}

// ---------------- CSR build: partition + LDS counting sort ----------------
// Pass A: per-block x per-range histogram (LDS only).
__global__ __launch_bounds__(512) void partA_k(const int* __restrict__ dst,
                                               int* __restrict__ gcnt) {
    __shared__ int cnt[NGRP2];
    int b = blockIdx.x, t = threadIdx.x;
    for (int i = t; i < NGRP2; i += 512) cnt[i] = 0;
    __syncthreads();
    int e_beg = b * EPB;
    for (int e = e_beg + t; e < e_beg + EPB; e += 512)
        atomicAdd(&cnt[dst[e] / GR2], 1);
    __syncthreads();
    for (int i = t; i < NGRP2; i += 512) gcnt[i * NPB + b] = cnt[i];
}

// Hierarchical exclusive scan of gcnt (51200 = PSB*1024, g-major).
__global__ __launch_bounds__(1024) void psumA_k(const int* __restrict__ gcnt,
                                                int* __restrict__ psum) {
    __shared__ int sh[1024];
    int b = blockIdx.x, t = threadIdx.x;
    sh[t] = gcnt[b * 1024 + t];
    __syncthreads();
    for (int off = 512; off; off >>= 1) {
        if (t < off) sh[t] += sh[t + off];
        __syncthreads();
    }
    if (t == 0) psum[b] = sh[0];
}

__global__ __launch_bounds__(64) void psumB_k(const int* __restrict__ psum,
                                              int* __restrict__ poffb,
                                              int* __restrict__ rowptr) {
    __shared__ int sh[64];
    int t = threadIdx.x;
    int v = (t < PSB) ? psum[t] : 0;
    sh[t] = v;
    __syncthreads();
    for (int off = 1; off < 64; off <<= 1) {
        int u = (t >= off) ? sh[t - off] : 0;
        __syncthreads();
        sh[t] += u;
        __syncthreads();
    }
    if (t < PSB) poffb[t] = sh[t] - v;
    if (t == 0) rowptr[NN] = EE;
}

__global__ __launch_bounds__(1024) void psumC_k(const int* __restrict__ gcnt,
                                                const int* __restrict__ poffb,
                                                int* __restrict__ poff) {
    __shared__ int sh[1024];
    int b = blockIdx.x, t = threadIdx.x;
    int v = gcnt[b * 1024 + t];
    sh[t] = v;
    __syncthreads();
    for (int off = 1; off < 1024; off <<= 1) {
        int u = (t >= off) ? sh[t - off] : 0;
        __syncthreads();
        sh[t] += u;
        __syncthreads();
    }
    poff[b * 1024 + t] = sh[t] - v + poffb[b];
}

// Pass B: partition edges; PACKED 4B entries: src (17b) | (d%GR2)<<17 (9b).
__global__ __launch_bounds__(512) void partB_k(const int* __restrict__ src,
                                               const int* __restrict__ dst,
                                               const int* __restrict__ poff,
                                               int* __restrict__ ebuf) {
    __shared__ int cur[NGRP2];
    int b = blockIdx.x, t = threadIdx.x;
    for (int i = t; i < NGRP2; i += 512) cur[i] = poff[i * NPB + b];
    __syncthreads();
    int e_beg = b * EPB;
    for (int e = e_beg + t; e < e_beg + EPB; e += 512) {
        int d = dst[e], s = src[e];
        int g = d / GR2;
        int p = atomicAdd(&cur[g], 1);
        ebuf[p] = s | ((d - g * GR2) << 17);
    }
}

// Pass C: per-range LDS counting sort; derives rowptr locally.
__global__ __launch_bounds__(512) void partC_k(const int* __restrict__ ebuf,
                                               const int* __restrict__ poff,
                                               int* __restrict__ rowptr,
                                               int* __restrict__ csr_src) {
    __shared__ int lsrc[CCAP];
    __shared__ int ldeg[512];
    __shared__ int ssc[512];
    __shared__ int lcur[512];
    int g = blockIdx.x, t = threadIdx.x;
    int nbase = g * GR2;
    int beg = poff[g * NPB];
    int end = (g == NGRP2 - 1) ? EE : poff[(g + 1) * NPB];
    ldeg[t] = 0;
    __syncthreads();
    for (int e = beg + t; e < end; e += 512)
        atomicAdd(&ldeg[ebuf[e] >> 17], 1);
    __syncthreads();
    int v = ldeg[t];
    ssc[t] = v;
    __syncthreads();
    for (int off = 1; off < 512; off <<= 1) {
        int u = (t >= off) ? ssc[t - off] : 0;
        __syncthreads();
        ssc[t] += u;
        __syncthreads();
    }
    int ex = ssc[t] - v;
    lcur[t] = ex;
    if (t < GR2) rowptr[nbase + t] = beg + ex;
    __syncthreads();
    for (int e = beg + t; e < end; e += 512) {
        int pk = ebuf[e];
        int p = atomicAdd(&lcur[pk >> 17], 1);
        if (p < CCAP) lsrc[p] = pk & 0x1FFFF;
    }
    __syncthreads();
    int len = end - beg; if (len > CCAP) len = CCAP;
    for (int i = t; i < len; i += 512) csr_src[beg + i] = lsrc[i];
}

// ---------- fused per-node softmax + aggregation (software-pipelined) ----------
// ONE WAVE PER WORKGROUP. Two-stage pipeline: while chunk k's 32 h-row loads
// are in flight and its FMAs run, chunk k+1's csr/el/exp state is computed in
// the shadow -- removes the csr->el->exp front-end latency from the steady
// state. Alpha broadcast via static ds_swizzle pattern (lane&16)|i.
#define BC16(x, I) __uint_as_float(__builtin_amdgcn_ds_swizzle( \
    __float_as_uint(x), ((I) << 5) | 0x10))

#define AGG_STEP(av, hvp, I)                      \
    {                                             \
        float ai = BC16(av, I);                   \
        float2 f = __half22float2((hvp)[I]);      \
        acc0 = fmaf(ai, f.x, acc0);               \
        acc1 = fmaf(ai, f.y, acc1);               \
    }

#define AGG16(av, hvp)                                                       \
    AGG_STEP(av, hvp, 0)  AGG_STEP(av, hvp, 1)  AGG_STEP(av, hvp, 2)         \
    AGG_STEP(av, hvp, 3)  AGG_STEP(av, hvp, 4)  AGG_STEP(av, hvp, 5)         \
    AGG_STEP(av, hvp, 6)  AGG_STEP(av, hvp, 7)  AGG_STEP(av, hvp, 8)         \
    AGG_STEP(av, hvp, 9)  AGG_STEP(av, hvp, 10) AGG_STEP(av, hvp, 11)        \
    AGG_STEP(av, hvp, 12) AGG_STEP(av, hvp, 13) AGG_STEP(av, hvp, 14)        \
    AGG_STEP(av, hvp, 15)

template <int FINAL>
__global__ __launch_bounds__(64) void gat_agg_k(const int* __restrict__ rowptr,
                                                const int* __restrict__ csr_src,
                                                const float* __restrict__ el,
                                                const float* __restrict__ er,
                                                const __half* __restrict__ h,
                                                const float* __restrict__ bias,
                                                void* __restrict__ outv,
                                                const float* __restrict__ Wf,
                                                const float* __restrict__ bf) {
    int wave = blockIdx.x;
    int lane = threadIdx.x;
    int row = rowptr[wave], end = rowptr[wave + 1];
    int hd = lane >> 4, sub = lane & 15;
    float erd = er[wave * 4 + hd];
    const __half2* hbase = (const __half2*)h + lane;  // + si*64 per gather

    float dpart = 0.f, acc0 = 0.f, acc1 = 0.f;
    int s0 = 0, s1 = 0;
    float a0 = 0.f, a1 = 0.f;

    // pipeline stage 1: chunk-state loader (csr gather -> el gather -> exp)
    auto mk = [&](int b) {
        int c = end - b;
        s0 = csr_src[b + (sub < c ? sub : 0)];
        float v0 = el[s0 * 4 + hd] + erd;
        v0 = (v0 >= 0.f) ? v0 : 0.2f * v0;
        a0 = (sub < c) ? __expf(v0) : 0.f;
        if (c > 16) {
            int i1 = 16 + sub;
            s1 = csr_src[b + (i1 < c ? i1 : 0)];
            float v1 = el[s1 * 4 + hd] + erd;
            v1 = (v1 >= 0.f) ? v1 : 0.2f * v1;
            a1 = (i1 < c) ? __expf(v1) : 0.f;
        } else {
            s1 = s0;
            a1 = 0.f;
        }
    };
    if (row < end) mk(row);

    for (int base = row; base < end; ) {
        int nb = base + 32;
        int c = end - base;
        int cs0 = s0, cs1 = s1;
        float ca0 = a0, ca1 = a1;
        dpart += ca0 + ca1;
        __half2 hv[32];
#pragma unroll
        for (int i = 0; i < 16; ++i) {
            int si = __builtin_amdgcn_readlane(cs0, i);
            hv[i] = hbase[si * 64];
        }
        if (c > 16) {
#pragma unroll
            for (int i = 0; i < 16; ++i) {
                int si = __builtin_amdgcn_readlane(cs1, i);
                hv[16 + i] = hbase[si * 64];
            }
        }
        if (nb < end) mk(nb);   // prefetch next chunk under current loads
        AGG16(ca0, hv)
        if (c > 16) {
            AGG16(ca1, (hv + 16))
        }
        base = nb;
    }
    float denom = dpart;
#pragma unroll
    for (int off = 1; off < 16; off <<= 1) denom += __shfl_xor(denom, off, 64);
    float inv = 1.f / fmaxf(denom, 1e-9f);
    float2 bv = *(const float2*)&bias[lane * 2];
    float o0 = acc0 * inv + bv.x;
    float o1 = acc1 * inv + bv.y;

    if (FINAL) {
        float* out = (float*)outv;
        float4 wf = *(const float4*)&Wf[lane * 4];
        float c0 = o0 * wf.x + o1 * wf.z;
        float c1 = o0 * wf.y + o1 * wf.w;
#pragma unroll
        for (int off = 1; off < 64; off <<= 1) {
            c0 += __shfl_xor(c0, off, 64);
            c1 += __shfl_xor(c1, off, 64);
        }
        if (lane == 0) {
            float2 res = make_float2(c0 + bf[0], c1 + bf[1]);
            *(float2*)&out[(size_t)wave * 2] = res;
        }
    } else {
        __half* out = (__half*)outv;
        *(__half2*)&out[(size_t)wave * 128 + lane * 2] = __floats2half2_rn(o0, o1);
    }
}

extern "C" void kernel_launch(void* const* d_in, const int* in_sizes, int n_in,
                              void* d_out, int out_size, void* d_ws, size_t ws_size,
                              hipStream_t stream) {
    const float* x   = (const float*)d_in[0];
    const int*   src = (const int*)d_in[1];
    const int*   dst = (const int*)d_in[2];
    const float* W1  = (const float*)d_in[3];
    const float* al1 = (const float*)d_in[4];
    const float* ar1 = (const float*)d_in[5];
    const float* b1  = (const float*)d_in[6];
    const float* W2  = (const float*)d_in[7];
    const float* al2 = (const float*)d_in[8];
    const float* ar2 = (const float*)d_in[9];
    const float* b2  = (const float*)d_in[10];
    const float* Wf  = (const float*)d_in[11];
    const float* bf  = (const float*)d_in[12];
    float* out = (float*)d_out;

    __half* bufH  = (__half*)d_ws;                       // N*128 fp16 (h)
    __half* bufO  = bufH + (size_t)NN * 128;             // N*128 fp16 (layer1 out)
    float* el     = (float*)(bufO + (size_t)NN * 128);   // N*4
    float* er     = el + NN * 4;                         // N*4
    int* rowptr   = (int*)(er + NN * 4);                 // N+2 (padded even)
    int* csr_src  = rowptr + NN + 2;                     // E
    int* ebuf     = csr_src + EE;                        // E (packed 4B)
    int* gcnt     = ebuf + EE;                           // NGRP2*NPB
    int* poff     = gcnt + NGRP2 * NPB;                  // NGRP2*NPB
    int* psum     = poff + NGRP2 * NPB;                  // PSB
    int* poffb    = psum + PSB;                          // PSB
    __half* Wt1   = (__half*)(poffb + PSB);              // 128*128 fp16
    __half* Wt2   = Wt1 + 128 * 128;                     // 128*128 fp16

    const int T = 256;
    int gGemm = (NN + 63) / 64;    // 64 rows per block

    // W pre-transpose/convert + CSR build
    wtrans_k<<<128, T, 0, stream>>>(W1, W2, Wt1, Wt2);
    partA_k<<<NPB, 512, 0, stream>>>(dst, gcnt);
    psumA_k<<<PSB, 1024, 0, stream>>>(gcnt, psum);
    psumB_k<<<1, 64, 0, stream>>>(psum, poffb, rowptr);
    psumC_k<<<PSB, 1024, 0, stream>>>(gcnt, poffb, poff);
    partB_k<<<NPB, 512, 0, stream>>>(src, dst, poff, ebuf);
    partC_k<<<NGRP2, 512, 0, stream>>>(ebuf, poff, rowptr, csr_src);

    // layer 1
    gemm_el_k<0><<<gGemm, T, 0, stream>>>(x, Wt1, al1, ar1, bufH, el, er);
    gat_agg_k<0><<<NN, 64, 0, stream>>>(rowptr, csr_src, el, er, bufH, b1, bufO,
                                        nullptr, nullptr);
    // layer 2 (classifier fused into aggregation epilogue)
    gemm_el_k<1><<<gGemm, T, 0, stream>>>(bufO, Wt2, al2, ar2, bufH, el, er);
    gat_agg_k<1><<<NN, 64, 0, stream>>>(rowptr, csr_src, el, er, bufH, b2, out,
                                        Wf, bf);
}